// Round 12
// baseline (8370.481 us; speedup 1.0000x reference)
//
#include <hip/hip_runtime.h>
#include <hip/hip_bf16.h>
#include <cstddef>

#define S_LEN 512
#define BATCH 64
#define HID 256
#define G3 768
#define SB (S_LEN*BATCH)
#define D2 512
#define L2E 1.44269504f

typedef unsigned short u16;
typedef __attribute__((ext_vector_type(8))) short s16x8;
typedef __attribute__((ext_vector_type(8))) _Float16 f16x8;
typedef __attribute__((ext_vector_type(4))) float f32x4;

__device__ __forceinline__ float bf2f(u16 u) {
    return __uint_as_float(((unsigned)u) << 16);
}
__device__ __forceinline__ u16 f2bf(float f) {
    unsigned u = __float_as_uint(f);
    unsigned r = (u + 0x7FFFu + ((u >> 16) & 1u)) >> 16;
    return (u16)r;
}
__device__ __forceinline__ float fast_rcp(float x) {
#if __has_builtin(__builtin_amdgcn_rcpf)
    return __builtin_amdgcn_rcpf(x);
#else
    return 1.f / x;
#endif
}
__device__ __forceinline__ float fast_exp2(float x) {
#if __has_builtin(__builtin_amdgcn_exp2f)
    return __builtin_amdgcn_exp2f(x);
#else
    return __expf(x * 0.69314718f);
#endif
}
__device__ __forceinline__ void gload_lds16(const void* g, void* l) {
    __builtin_amdgcn_global_load_lds((const __attribute__((address_space(1))) void*)g,
                                     (__attribute__((address_space(3))) void*)l, 16, 0, 0);
}

// ---------- prep kernels ----------
__global__ void f32_to_bf16(const float* __restrict__ in, u16* __restrict__ out, long n) {
    long i = (long)blockIdx.x * 256 + threadIdx.x;
    if (i < n) out[i] = f2bf(in[i]);
}
// w_ih scaled: gate rows g<512 ×log2e, g>=512 ×2log2e (exp2 prescale)
__global__ void f32_to_bf16_gs(const float* __restrict__ in, u16* __restrict__ out,
                               long n, int K) {
    long i = (long)blockIdx.x * 256 + threadIdx.x;
    if (i >= n) return;
    int g = (int)((i / K) % 768);
    float sc = (g < 512) ? L2E : (2.f * L2E);
    out[i] = f2bf(in[i] * sc);
}
// w_hh -> f16 native layout [12][768][256], exp2-prescaled per gate
__global__ void f32_to_f16_gs(const float* __restrict__ in, _Float16* __restrict__ out, long n) {
    long i = (long)blockIdx.x * 256 + threadIdx.x;
    if (i >= n) return;
    int g = (int)((i / 256) % 768);
    float sc = (g < 512) ? L2E : (2.f * L2E);
    out[i] = (_Float16)(in[i] * sc);
}
// biasT[l][d][g]: g<512 -> (b_ih+b_hh)*log2e ; g>=512 -> b_ih*2log2e
__global__ void add_bias(const float* __restrict__ bih0, const float* __restrict__ bihl,
                         const float* __restrict__ bhh, float* __restrict__ outb) {
    int i = blockIdx.x * 256 + threadIdx.x;
    if (i >= 6 * 1536) return;
    int l = i / 1536, r = i - l * 1536;
    int g = r % 768;
    float bi = (l == 0) ? bih0[r] : bihl[(l - 1) * 1536 + r];
    outb[i] = (g < 512) ? (bi + bhh[i]) * L2E : bi * (2.f * L2E);
}

// ---------- input GEMM (MFMA) ----------
__global__ __launch_bounds__(256, 2) void gemm_mfma(
    const u16* __restrict__ A,
    const u16* __restrict__ Bt,
    const float* __restrict__ bias,
    u16* __restrict__ Cg,
    int K)
{
    int d = blockIdx.z;
    const u16* Bb = Bt + (size_t)d * 768 * K;
    const float* bi = bias + d * G3;
    u16* Cm = Cg + (size_t)d * SB * G3;

    int n0 = blockIdx.x * 128;
    int m0 = blockIdx.y * 128;
    int tid = threadIdx.x;
    int wave = tid >> 6, lane = tid & 63;
    int wm = wave >> 1, wn = wave & 1;

    __shared__ u16 Asm[128 * 32];
    __shared__ u16 Bsm[128 * 32];

    f32x4 acc[4][4] = {};

    for (int k0 = 0; k0 < K; k0 += 32) {
#pragma unroll
        for (int p = 0; p < 2; p++) {
            int c = p * 256 + wave * 64 + lane;
            int row = c >> 2, kc = c & 3;
            const u16* srcA = A + (size_t)(m0 + row) * K + k0 + kc * 8;
            const u16* srcB = Bb + (size_t)(n0 + row) * K + k0 + kc * 8;
            gload_lds16(srcA, &Asm[(p * 256 + wave * 64) * 8]);
            gload_lds16(srcB, &Bsm[(p * 256 + wave * 64) * 8]);
        }
        __syncthreads();

        s16x8 af[4], bfr[4];
#pragma unroll
        for (int i = 0; i < 4; i++) {
            int arow = wm * 64 + i * 16 + (lane & 15);
            af[i] = *reinterpret_cast<const s16x8*>(&Asm[arow * 32 + (lane >> 4) * 8]);
            int brow = wn * 64 + i * 16 + (lane & 15);
            bfr[i] = *reinterpret_cast<const s16x8*>(&Bsm[brow * 32 + (lane >> 4) * 8]);
        }
#pragma unroll
        for (int i = 0; i < 4; i++)
#pragma unroll
            for (int j = 0; j < 4; j++)
                acc[i][j] = __builtin_amdgcn_mfma_f32_16x16x32_bf16(af[i], bfr[j], acc[i][j], 0, 0, 0);
        __syncthreads();
    }

    int lcol = lane & 15, lrow4 = (lane >> 4) * 4;
#pragma unroll
    for (int i = 0; i < 4; i++) {
#pragma unroll
        for (int j = 0; j < 4; j++) {
            int n = n0 + wn * 64 + j * 16 + lcol;
            float bv = bi[n];
#pragma unroll
            for (int q = 0; q < 4; q++) {
                int m = m0 + wm * 64 + i * 16 + lrow4 + q;
                Cm[(size_t)m * G3 + n] = f2bf(acc[i][j][q] + bv);
            }
        }
    }
}

// ---------- MFMA recurrent scan (R11 + swizzled gi + gi-folded C-init) ----------
// 8 blocks (4 batch-groups x 2 dirs) x 512 threads (8 waves).
// Wave wv owns columns c0 = wv*16+lr and c1 = c0+128, ALL 3 gates in-lane.
// gi: DMA with pre-swizzled SOURCE (chunk ^= ((row>>2)&3)<<1, LDS linear) so the
// per-lane scalar reads are bank-conflict-free; r/z gi folded into MFMA C-init.
__global__ __launch_bounds__(512, 2) void scan_mfma(
    const _Float16* __restrict__ whh16,  // [12][768][256] f16, exp2-prescaled
    const u16* __restrict__ gi,          // [2][SB][768] bf16 prescaled, r/z b_hh folded
    const float* __restrict__ bhh,       // [6][2][768] f32 raw (n-gate term)
    const float* __restrict__ h0,        // [12][64][256] f32
    u16* __restrict__ outc,              // [SB][512] bf16 (scratch on last layer)
    float* __restrict__ finals,          // [12][64][256] f32
    int layer)
{
    int b0 = blockIdx.x * 16;
    int d  = blockIdx.y;
    int ld = layer * 2 + d;
    int tid = threadIdx.x;
    int wv = tid >> 6, lane = tid & 63;
    int lr = lane & 15;
    int lq = lane >> 4;
    int r0 = lq * 4;

    // h: [2][4096] f16; elem (row,k) at idx (k>>5)*512 + ((k>>3)&3)*128 + row*8 + (k&7)
    __shared__ alignas(16) _Float16 hT[2][4096];   // 16 KB
    __shared__ alignas(16) u16 gT[2][16][G3];      // 48 KB -> 64 KiB total

    const _Float16* Wl = whh16 + (size_t)ld * G3 * HID;
    const u16* gid = gi + (size_t)d * (size_t)SB * G3;

    int c0 = wv * 16 + lr;
    int c1 = c0 + 128;

    // ---- persistent weight B-frags (unified-file resident), pinned vs remat
    f16x8 w[6][8];
#pragma unroll
    for (int kt = 0; kt < 8; kt++) {
        w[0][kt] = *reinterpret_cast<const f16x8*>(Wl + (size_t)(c0)       * HID + kt * 32 + lq * 8);
        w[1][kt] = *reinterpret_cast<const f16x8*>(Wl + (size_t)(c1)       * HID + kt * 32 + lq * 8);
        w[2][kt] = *reinterpret_cast<const f16x8*>(Wl + (size_t)(256 + c0) * HID + kt * 32 + lq * 8);
        w[3][kt] = *reinterpret_cast<const f16x8*>(Wl + (size_t)(256 + c1) * HID + kt * 32 + lq * 8);
        w[4][kt] = *reinterpret_cast<const f16x8*>(Wl + (size_t)(512 + c0) * HID + kt * 32 + lq * 8);
        w[5][kt] = *reinterpret_cast<const f16x8*>(Wl + (size_t)(512 + c1) * HID + kt * 32 + lq * 8);
#pragma unroll
        for (int i = 0; i < 6; i++) asm volatile("" : "+v"(w[i][kt]));
    }

    float bhn0 = bhh[(size_t)ld * G3 + 512 + c0] * (2.f * L2E);
    float bhn1 = bhh[(size_t)ld * G3 + 512 + c1] * (2.f * L2E);

    // ---- h0 -> hreg (f32) + hT[0]
    const int hwb0 = (c0 >> 3) * 128 + lq * 32 + (c0 & 7);   // +q*8; c1 adds +2048
    float hreg0[4], hreg1[4];
#pragma unroll
    for (int q = 0; q < 4; q++) {
        float hv0 = h0[(size_t)ld * BATCH * HID + (b0 + r0 + q) * HID + c0];
        float hv1 = h0[(size_t)ld * BATCH * HID + (b0 + r0 + q) * HID + c1];
        hreg0[q] = hv0; hreg1[q] = hv1;
        hT[0][hwb0 + q * 8] = (_Float16)hv0;
        hT[0][hwb0 + 2048 + q * 8] = (_Float16)hv1;
    }

    // ---- per-lane PRE-SWIZZLED DMA source offsets (LDS dest stays linear):
    // LDS byte B = wv*3072 + i*1024 + lane*16 holds global chunk j^key(row),
    // key(row) = ((row>>2)&3)<<1  (involution; read side applies same XOR)
    int soff[3];
#pragma unroll
    for (int i = 0; i < 3; i++) {
        int B = wv * 3072 + i * 1024 + lane * 16;
        int r = B / 1536;
        int j = (B - r * 1536) >> 4;
        int pj = j ^ (((r >> 2) & 3) << 1);
        soff[i] = r * 1536 + pj * 16;
    }

    auto dma_gi = [&](int s, int buf) {
        const char* src = (const char*)(gid + ((size_t)s * BATCH + b0) * G3);
        char* dst = (char*)&gT[buf][0][0];
#pragma unroll
        for (int i = 0; i < 3; i++)
            gload_lds16(src + soff[i], dst + wv * 3072 + i * 1024);
    };

    dma_gi(d ? (S_LEN - 1) : 0, 0);
    asm volatile("s_waitcnt vmcnt(0)" ::: "memory");
    __syncthreads();

    // swizzled per-lane gi read base (bytes within a buffer):
    // row = lq*4+q (key = lq), chunk = gate*32 + cx*16 + 2*(wv^lq) + (lr>>3)
    const int grb = (2 * (wv ^ lq) + (lr >> 3)) * 16 + (lr & 7) * 2;

    auto step_body = [&](int t, const int par) {
        int s = d ? (S_LEN - 1 - t) : t;
        // 1. issue next step's gi DMA; pin issue position before the rest
        if (t + 1 < S_LEN) dma_gi(d ? (s - 1) : (s + 1), par ^ 1);
        __builtin_amdgcn_sched_barrier(0);

        // 2. gi reads (conflict-free) BEFORE the MFMA block; r/z fold into C-init
        const char* gb = (const char*)&gT[par][0][0] + lq * 4 * 1536 + grb;
        f32x4 acc[6];
        float gin0[4], gin1[4];
#pragma unroll
        for (int q = 0; q < 4; q++) {
            acc[0][q] = bf2f(*(const u16*)(gb + q * 1536));          // r,c0
            acc[1][q] = bf2f(*(const u16*)(gb + q * 1536 + 256));    // r,c1
            acc[2][q] = bf2f(*(const u16*)(gb + q * 1536 + 512));    // z,c0
            acc[3][q] = bf2f(*(const u16*)(gb + q * 1536 + 768));    // z,c1
            gin0[q]   = bf2f(*(const u16*)(gb + q * 1536 + 1024));   // n,c0
            gin1[q]   = bf2f(*(const u16*)(gb + q * 1536 + 1280));   // n,c1
            acc[4][q] = 0.f; acc[5][q] = 0.f;
        }

        // 3. gate matmul from hT[par]; acc[0..3] already hold gi_r/gi_z
#pragma unroll
        for (int kt = 0; kt < 8; kt++) {
            f16x8 a = *(const f16x8*)&hT[par][kt * 512 + lq * 128 + lr * 8];
#pragma unroll
            for (int i = 0; i < 6; i++)
                acc[i] = __builtin_amdgcn_mfma_f32_16x16x32_f16(a, w[i][kt], acc[i], 0, 0, 0);
        }

        // 4. GRU update; h -> hT[par^1]; outc stores
        size_t ob = ((size_t)s * BATCH + b0 + r0) * D2 + d * HID;
#pragma unroll
        for (int q = 0; q < 4; q++) {
            {
                float r = fast_rcp(1.f + fast_exp2(-acc[0][q]));
                float z = fast_rcp(1.f + fast_exp2(-acc[2][q]));
                float xn2 = gin0[q] + r * (acc[4][q] + bhn0);
                float n = 1.f - 2.f * fast_rcp(fast_exp2(xn2) + 1.f);
                float hn = n + z * (hreg0[q] - n);
                hreg0[q] = hn;
                hT[par ^ 1][hwb0 + q * 8] = (_Float16)hn;
                outc[ob + q * D2 + c0] = f2bf(hn);
            }
            {
                float r = fast_rcp(1.f + fast_exp2(-acc[1][q]));
                float z = fast_rcp(1.f + fast_exp2(-acc[3][q]));
                float xn2 = gin1[q] + r * (acc[5][q] + bhn1);
                float n = 1.f - 2.f * fast_rcp(fast_exp2(xn2) + 1.f);
                float hn = n + z * (hreg1[q] - n);
                hreg1[q] = hn;
                hT[par ^ 1][hwb0 + 2048 + q * 8] = (_Float16)hn;
                outc[ob + q * D2 + c1] = f2bf(hn);
            }
        }
        // 5. one barrier; vmcnt(8) drains the 3 gi DMAs but not the 8 outc stores
        asm volatile("s_waitcnt vmcnt(8) lgkmcnt(0)" ::: "memory");
        __builtin_amdgcn_s_barrier();
        __builtin_amdgcn_sched_barrier(0);
    };

    for (int t2 = 0; t2 < S_LEN; t2 += 2) {
        step_body(t2, 0);
        step_body(t2 + 1, 1);
    }

#pragma unroll
    for (int q = 0; q < 4; q++) {
        finals[(size_t)ld * BATCH * HID + (b0 + r0 + q) * HID + c0] = hreg0[q];
        finals[(size_t)ld * BATCH * HID + (b0 + r0 + q) * HID + c1] = hreg1[q];
    }
}

extern "C" void kernel_launch(void* const* d_in, const int* in_sizes, int n_in,
                              void* d_out, int out_size, void* d_ws, size_t ws_size,
                              hipStream_t stream) {
    const float* x     = (const float*)d_in[0];
    const float* h0    = (const float*)d_in[1];
    const float* w_ih0 = (const float*)d_in[2];
    const float* b_ih0 = (const float*)d_in[3];
    const float* w_ih  = (const float*)d_in[4];
    const float* b_ih  = (const float*)d_in[5];
    const float* w_hh  = (const float*)d_in[6];
    const float* b_hh  = (const float*)d_in[7];
    float* out = (float*)d_out;

    char* ws = (char*)d_ws;
    _Float16* whh16 = (_Float16*)(ws + 0);
    u16* wbf0  = (u16*)(ws + 4718592);
    u16* wbfl  = (u16*)(ws + 5111808);
    float* biasT = (float*)(ws + 12976128);
    u16* gi    = (u16*)(ws + 13012992);
    u16* curA  = (u16*)(ws + 113676288);
    u16* curB  = (u16*)(ws + 147230720);

    f32_to_f16_gs<<<(2359296 + 255) / 256, 256, 0, stream>>>(w_hh, whh16, 2359296L);
    f32_to_bf16_gs<<<(196608 + 255) / 256, 256, 0, stream>>>(w_ih0, wbf0, 196608L, 128);
    f32_to_bf16_gs<<<(3932160 + 255) / 256, 256, 0, stream>>>(w_ih, wbfl, 3932160L, 512);
    f32_to_bf16<<<(4194304 + 255) / 256, 256, 0, stream>>>(x, curA, 4194304L);
    add_bias<<<(9216 + 255) / 256, 256, 0, stream>>>(b_ih0, b_ih, b_hh, biasT);

    u16* cin = curA;
    u16* cout_ = curB;
    for (int l = 0; l < 6; l++) {
        int K = l ? 512 : 128;
        const u16* wt = l ? (wbfl + (size_t)(l - 1) * 2 * 768 * 512) : wbf0;
        const float* bi = biasT + (size_t)l * 1536;
        dim3 g(6, 256, 2);
        gemm_mfma<<<g, 256, 0, stream>>>(cin, wt, bi, gi, K);
        scan_mfma<<<dim3(4, 2), 512, 0, stream>>>(whh16, gi, b_hh, h0,
                                                  cout_, out, l);
        u16* tmp = cin; cin = cout_; cout_ = tmp;
    }
}

// Round 13
// 4066.403 us; speedup vs baseline: 2.0584x; 2.0584x over previous
//
#include <hip/hip_runtime.h>
#include <hip/hip_bf16.h>
#include <cstddef>

#define S_LEN 512
#define BATCH 64
#define HID 256
#define G3 768
#define SB (S_LEN*BATCH)
#define D2 512
#define L2E 1.44269504f

typedef unsigned short u16;
typedef _Float16 h2v __attribute__((ext_vector_type(2)));
typedef __attribute__((ext_vector_type(8))) short s16x8;
typedef __attribute__((ext_vector_type(4))) float f32x4;

__device__ __forceinline__ float bf2f(u16 u) {
    return __uint_as_float(((unsigned)u) << 16);
}
__device__ __forceinline__ u16 f2bf(float f) {
    unsigned u = __float_as_uint(f);
    unsigned r = (u + 0x7FFFu + ((u >> 16) & 1u)) >> 16;
    return (u16)r;
}
__device__ __forceinline__ u16 f2h_bits(float f) {
    _Float16 h = (_Float16)f;
    union { _Float16 h; u16 u; } cv; cv.h = h;
    return cv.u;
}
__device__ __forceinline__ h2v u2h(unsigned u) {
    union { unsigned u; h2v h; } cv; cv.u = u;
    return cv.h;
}
__device__ __forceinline__ float dot2f(unsigned w, unsigned h, float acc) {
#if __has_builtin(__builtin_amdgcn_fdot2)
    return __builtin_amdgcn_fdot2(u2h(w), u2h(h), acc, false);
#else
    h2v wv = u2h(w), hv = u2h(h);
    return acc + (float)wv.x * (float)hv.x + (float)wv.y * (float)hv.y;
#endif
}
__device__ __forceinline__ float fast_rcp(float x) {
#if __has_builtin(__builtin_amdgcn_rcpf)
    return __builtin_amdgcn_rcpf(x);
#else
    return 1.f / x;
#endif
}
__device__ __forceinline__ float fast_exp2(float x) {
#if __has_builtin(__builtin_amdgcn_exp2f)
    return __builtin_amdgcn_exp2f(x);
#else
    return __expf(x * 0.69314718f);
#endif
}
__device__ __forceinline__ void gload_lds16(const void* g, void* l) {
    __builtin_amdgcn_global_load_lds((const __attribute__((address_space(1))) void*)g,
                                     (__attribute__((address_space(3))) void*)l, 16, 0, 0);
}

// ---------- prep kernels ----------
__global__ void f32_to_bf16(const float* __restrict__ in, u16* __restrict__ out, long n) {
    long i = (long)blockIdx.x * 256 + threadIdx.x;
    if (i < n) out[i] = f2bf(in[i]);
}
// w_ih scaled: gate rows g<512 ×log2e, g>=512 ×2log2e (exp2 prescale)
__global__ void f32_to_bf16_gs(const float* __restrict__ in, u16* __restrict__ out,
                               long n, int K) {
    long i = (long)blockIdx.x * 256 + threadIdx.x;
    if (i >= n) return;
    int g = (int)((i / K) % 768);
    float sc = (g < 512) ? L2E : (2.f * L2E);
    out[i] = f2bf(in[i] * sc);
}
// Pair-split weight pack: wpack2[mat][j][lane], j in [0,128).
// lane parity p = lane&1 owns k-half [128p,128p+128); g0 = lane&~1.
//   j<64 : gate g0,   kpair = 64p + j
//   j>=64: gate g0+1, kpair = 64p + (j-64)
// u32 = half2( W[gate][2kp], W[gate][2kp+1] ) * gate_scale (exp2 prescale)
__global__ void pack_whh_pair(const float* __restrict__ in, unsigned* __restrict__ out,
                              long total) {
    long i = (long)blockIdx.x * 256 + threadIdx.x;
    if (i >= total) return;
    long mat = i / (128L * G3);
    long rem = i - mat * (128L * G3);
    int j = (int)(rem / G3);
    int lane = (int)(rem - (long)j * G3);
    int p = lane & 1;
    int g0 = lane & ~1;
    int gate = (j < 64) ? g0 : (g0 + 1);
    int kp = 64 * p + ((j < 64) ? j : (j - 64));
    float sc = (gate < 512) ? L2E : (2.f * L2E);
    const float* base = in + mat * (768L * 256) + (long)gate * 256 + 2 * kp;
    unsigned lo = f2h_bits(base[0] * sc);
    unsigned hi = f2h_bits(base[1] * sc);
    out[i] = lo | (hi << 16);
}
// biasT[l][d][g]: g<512 -> (b_ih+b_hh)*log2e ; g>=512 -> b_ih*2log2e
__global__ void add_bias(const float* __restrict__ bih0, const float* __restrict__ bihl,
                         const float* __restrict__ bhh, float* __restrict__ outb) {
    int i = blockIdx.x * 256 + threadIdx.x;
    if (i >= 6 * 1536) return;
    int l = i / 1536, r = i - l * 1536;
    int g = r % 768;
    float bi = (l == 0) ? bih0[r] : bihl[(l - 1) * 1536 + r];
    outb[i] = (g < 512) ? (bi + bhh[i]) * L2E : bi * (2.f * L2E);
}

// ---------- input GEMM (MFMA) ----------
__global__ __launch_bounds__(256, 2) void gemm_mfma(
    const u16* __restrict__ A,
    const u16* __restrict__ Bt,
    const float* __restrict__ bias,
    u16* __restrict__ Cg,
    int K)
{
    int d = blockIdx.z;
    const u16* Bb = Bt + (size_t)d * 768 * K;
    const float* bi = bias + d * G3;
    u16* Cm = Cg + (size_t)d * SB * G3;

    int n0 = blockIdx.x * 128;
    int m0 = blockIdx.y * 128;
    int tid = threadIdx.x;
    int wave = tid >> 6, lane = tid & 63;
    int wm = wave >> 1, wn = wave & 1;

    __shared__ u16 Asm[128 * 32];
    __shared__ u16 Bsm[128 * 32];

    f32x4 acc[4][4] = {};

    for (int k0 = 0; k0 < K; k0 += 32) {
#pragma unroll
        for (int p = 0; p < 2; p++) {
            int c = p * 256 + wave * 64 + lane;
            int row = c >> 2, kc = c & 3;
            const u16* srcA = A + (size_t)(m0 + row) * K + k0 + kc * 8;
            const u16* srcB = Bb + (size_t)(n0 + row) * K + k0 + kc * 8;
            gload_lds16(srcA, &Asm[(p * 256 + wave * 64) * 8]);
            gload_lds16(srcB, &Bsm[(p * 256 + wave * 64) * 8]);
        }
        __syncthreads();

        s16x8 af[4], bfr[4];
#pragma unroll
        for (int i = 0; i < 4; i++) {
            int arow = wm * 64 + i * 16 + (lane & 15);
            af[i] = *reinterpret_cast<const s16x8*>(&Asm[arow * 32 + (lane >> 4) * 8]);
            int brow = wn * 64 + i * 16 + (lane & 15);
            bfr[i] = *reinterpret_cast<const s16x8*>(&Bsm[brow * 32 + (lane >> 4) * 8]);
        }
#pragma unroll
        for (int i = 0; i < 4; i++)
#pragma unroll
            for (int j = 0; j < 4; j++)
                acc[i][j] = __builtin_amdgcn_mfma_f32_16x16x32_bf16(af[i], bfr[j], acc[i][j], 0, 0, 0);
        __syncthreads();
    }

    int lcol = lane & 15, lrow4 = (lane >> 4) * 4;
#pragma unroll
    for (int i = 0; i < 4; i++) {
#pragma unroll
        for (int j = 0; j < 4; j++) {
            int n = n0 + wn * 64 + j * 16 + lcol;
            float bv = bi[n];
#pragma unroll
            for (int q = 0; q < 4; q++) {
                int m = m0 + wm * 64 + i * 16 + lrow4 + q;
                Cm[(size_t)m * G3 + n] = f2bf(acc[i][j][q] + bv);
            }
        }
    }
}

// ---------- recurrent scan (dot2, split-gate, pair-wise K-split) ----------
// One block per (batch row, direction); 768 threads; lane tid = gate tid.
// Pair (2i,2i+1): even lane reads h[0:128) only, odd lane h[128:256) only; each
// computes partials for BOTH pair gates over its half (weights repacked), then
// one shfl_xor(1)+add recombines. Halves the DS-read traffic vs R9.
__global__ __launch_bounds__(768, 3) void gru_scan(
    const unsigned* __restrict__ wpack2, // [12][128][768] u32, pair-split layout
    const float* __restrict__ bhh,       // [6][2][768] f32 raw
    const u16* __restrict__ gi,          // [2][SB][768] bf16 prescaled, r/z b_hh folded
    const float* __restrict__ h0,        // [12][64][256] f32
    u16* __restrict__ outc,              // [SB][512] bf16 (scratch on last layer)
    float* __restrict__ finals,          // [12][64][256] f32
    int layer)
{
    int b = blockIdx.x;
    int d = blockIdx.y;
    int tid = threadIdx.x;

    int ld = layer * 2 + d;
    const unsigned* Wp = wpack2 + (size_t)ld * 128 * G3 + tid;
    const u16* gid = gi + (size_t)d * SB * G3;

    __shared__ float rz_s[512];                    // r[0:256], z[256:512]
    __shared__ alignas(16) _Float16 h16_s[HID];
    __shared__ u16 gi_s[2][G3];

    unsigned wpk[128];
#pragma unroll
    for (int k = 0; k < 128; k++) wpk[k] = Wp[(size_t)k * G3];

    int gate = tid >> 8;          // 0=r, 1=z, 2=n
    int j = tid & 255;
    int p = tid & 1;              // k-half parity

    float hreg = 0.f, bhn = 0.f;
    if (gate == 2) {
        hreg = h0[(size_t)ld * BATCH * HID + b * HID + j];
        bhn = bhh[(size_t)ld * G3 + 512 + j] * (2.f * L2E);
        h16_s[j] = (_Float16)hreg;
    }
    {
        int s0 = d ? (S_LEN - 1) : 0;
        gi_s[0][tid] = gid[((size_t)s0 * BATCH + b) * G3 + tid];
    }
    __syncthreads();

    for (int t = 0; t < S_LEN; t++) {
        int s = d ? (S_LEN - 1 - t) : t;
        // prefetch next step's gi
        u16 ginext = 0;
        if (t + 1 < S_LEN) {
            int sn = d ? (s - 1) : (s + 1);
            ginext = gid[((size_t)sn * BATCH + b) * G3 + tid];
        }
        // dot over OWN k-half for both pair gates (2 chains each)
        const uint4* hp = reinterpret_cast<const uint4*>(h16_s) + p * 16;
        float a0 = 0.f, a1 = 0.f, b0v = 0.f, b1v = 0.f;
#pragma unroll
        for (int u = 0; u < 16; u += 2) {
            uint4 q0 = hp[u];
            uint4 q1 = hp[u + 1];
            a0 = dot2f(wpk[4 * u + 0], q0.x, a0);
            a0 = dot2f(wpk[4 * u + 1], q0.y, a0);
            a0 = dot2f(wpk[4 * u + 2], q0.z, a0);
            a0 = dot2f(wpk[4 * u + 3], q0.w, a0);
            a1 = dot2f(wpk[4 * u + 4], q1.x, a1);
            a1 = dot2f(wpk[4 * u + 5], q1.y, a1);
            a1 = dot2f(wpk[4 * u + 6], q1.z, a1);
            a1 = dot2f(wpk[4 * u + 7], q1.w, a1);
            b0v = dot2f(wpk[64 + 4 * u + 0], q0.x, b0v);
            b0v = dot2f(wpk[64 + 4 * u + 1], q0.y, b0v);
            b0v = dot2f(wpk[64 + 4 * u + 2], q0.z, b0v);
            b0v = dot2f(wpk[64 + 4 * u + 3], q0.w, b0v);
            b1v = dot2f(wpk[64 + 4 * u + 4], q1.x, b1v);
            b1v = dot2f(wpk[64 + 4 * u + 5], q1.y, b1v);
            b1v = dot2f(wpk[64 + 4 * u + 6], q1.z, b1v);
            b1v = dot2f(wpk[64 + 4 * u + 7], q1.w, b1v);
        }
        float pg0 = a0 + a1;     // partial for gate (tid&~1) over own half
        float pg1 = b0v + b1v;   // partial for gate (tid&~1)+1 over own half
        float own   = p ? pg1 : pg0;   // own gate's partial
        float other = p ? pg0 : pg1;   // partner gate's partial
        float recv = __shfl_xor(other, 1, 64);
        float acc = own + recv;

        float giv = bf2f(gi_s[t & 1][tid]);
        gi_s[(t + 1) & 1][tid] = ginext;
        // phase A: r/z lanes finish their gate from OWN acc
        if (gate < 2)
            rz_s[tid] = fast_rcp(1.f + fast_exp2(-(giv + acc)));
        __syncthreads();
        // phase B: n-lanes finish n-gate + h update
        if (gate == 2) {
            float r = rz_s[j];
            float z = rz_s[256 + j];
            float xn2 = giv + r * (acc + bhn);              // = 2*log2e * xn
            float n = 1.f - 2.f * fast_rcp(fast_exp2(xn2) + 1.f);
            float hn = n + z * (hreg - n);
            hreg = hn;
            h16_s[j] = (_Float16)hn;
            outc[((size_t)s * BATCH + b) * D2 + d * HID + j] = f2bf(hn);
        }
        __syncthreads();
    }
    if (gate == 2)
        finals[(size_t)ld * BATCH * HID + b * HID + j] = hreg;
}

extern "C" void kernel_launch(void* const* d_in, const int* in_sizes, int n_in,
                              void* d_out, int out_size, void* d_ws, size_t ws_size,
                              hipStream_t stream) {
    const float* x     = (const float*)d_in[0];
    const float* h0    = (const float*)d_in[1];
    const float* w_ih0 = (const float*)d_in[2];
    const float* b_ih0 = (const float*)d_in[3];
    const float* w_ih  = (const float*)d_in[4];
    const float* b_ih  = (const float*)d_in[5];
    const float* w_hh  = (const float*)d_in[6];
    const float* b_hh  = (const float*)d_in[7];
    float* out = (float*)d_out;

    char* ws = (char*)d_ws;
    // wpack2 u32 [12][128][768]   @ 0           4,718,592
    // wbf0  bf16 [2][768][128]    @ 4,718,592     393,216
    // wbfl  bf16 [5][2][768][512] @ 5,111,808   7,864,320
    // biasT f32 [6][2][768]       @ 12,976,128     36,864
    // gi    bf16 [2][SB][768]     @ 13,012,992 100,663,296
    // curA  bf16 [SB][512]        @ 113,676,288 33,554,432
    // curB  bf16 [SB][512]        @ 147,230,720 33,554,432
    unsigned* wpack2 = (unsigned*)(ws + 0);
    u16* wbf0  = (u16*)(ws + 4718592);
    u16* wbfl  = (u16*)(ws + 5111808);
    float* biasT = (float*)(ws + 12976128);
    u16* gi    = (u16*)(ws + 13012992);
    u16* curA  = (u16*)(ws + 113676288);
    u16* curB  = (u16*)(ws + 147230720);

    pack_whh_pair<<<(1179648 + 255) / 256, 256, 0, stream>>>(w_hh, wpack2, 1179648L);
    f32_to_bf16_gs<<<(196608 + 255) / 256, 256, 0, stream>>>(w_ih0, wbf0, 196608L, 128);
    f32_to_bf16_gs<<<(3932160 + 255) / 256, 256, 0, stream>>>(w_ih, wbfl, 3932160L, 512);
    f32_to_bf16<<<(4194304 + 255) / 256, 256, 0, stream>>>(x, curA, 4194304L);
    add_bias<<<(9216 + 255) / 256, 256, 0, stream>>>(b_ih0, b_ih, b_hh, biasT);

    u16* cin = curA;
    u16* cout_ = curB;
    for (int l = 0; l < 6; l++) {
        int K = l ? 512 : 128;
        const u16* wt = l ? (wbfl + (size_t)(l - 1) * 2 * 768 * 512) : wbf0;
        const float* bi = biasT + (size_t)l * 1536;
        dim3 g(6, 256, 2);
        gemm_mfma<<<g, 256, 0, stream>>>(cin, wt, bi, gi, K);
        gru_scan<<<dim3(64, 2), 768, 0, stream>>>(wpack2, b_hh, gi, h0,
                                                  cout_, out, l);
        u16* tmp = cin; cin = cout_; cout_ = tmp;
    }
}